// Round 1
// baseline (738.215 us; speedup 1.0000x reference)
//
#include <hip/hip_runtime.h>
#include <hip/hip_bf16.h>

#define N_ATOMS 100000
#define M_NBRS 12
#define ATOM_F 64
#define NBR_F 41
#define OUT_DIM 128   // 2*ATOM_F
#define IN_DIM 169    // 2*ATOM_F + NBR_F

typedef __attribute__((ext_vector_type(8))) short short8;
typedef __attribute__((ext_vector_type(4))) float f32x4;

__device__ __forceinline__ unsigned short f2bf(float f) {
    union { float f; unsigned u; } v; v.f = f;
    unsigned u = v.u;
    return (unsigned short)((u + 0x7fffu + ((u >> 16) & 1u)) >> 16);
}
__device__ __forceinline__ float bf2f(unsigned short h) {
    union { unsigned u; float f; } v; v.u = ((unsigned)h) << 16;
    return v.f;
}
__device__ __forceinline__ unsigned pack_bf2(float lo, float hi) {
    return (unsigned)f2bf(lo) | (((unsigned)f2bf(hi)) << 16);
}
__device__ __forceinline__ float softplus_f(float x) {
    return fmaxf(x, 0.f) + __logf(1.f + __expf(-fabsf(x)));
}
__device__ __forceinline__ float sigmoid_f(float x) {
    return 1.f / (1.f + __expf(-x));
}

// ---------------------------------------------------------------------------
// P: per-atom precompute. abf[i] = bf16(atom_fea[i]);  A1b[i][o] = bf16(
//    W_self[o]·a_i + b[o]).  MFMA 16x16x32, rows = 16 atoms, cols = 128.
// ---------------------------------------------------------------------------
__global__ __launch_bounds__(256, 4) void k_prep(
    const float* __restrict__ atom, const float* __restrict__ W,
    const float* __restrict__ bias, unsigned* __restrict__ abf_u32,
    unsigned short* __restrict__ A1b)
{
    __shared__ unsigned Ap[4 * 16 * 36];   // per-wave 16 rows x 36 dw (64 bf16 + pad)
    const int tid = threadIdx.x;
    const int w = tid >> 6, l = tid & 63;
    const int r = l & 15, g = l >> 4;

    // B fragments (W_self^T): lane holds B[k = g*8+kk*32+j][col = nt*16+r]
    short8 bf[8][2];
    #pragma unroll
    for (int nt = 0; nt < 8; ++nt)
      #pragma unroll
      for (int kk = 0; kk < 2; ++kk)
        #pragma unroll
        for (int j = 0; j < 8; ++j) {
            int col = nt * 16 + r;
            int k = g * 8 + kk * 32 + j;
            bf[nt][kk][j] = (short)f2bf(W[col * IN_DIM + k]);
        }

    const int totalw = gridDim.x * 4;
    const int gw = blockIdx.x * 4 + w;
    const int step = totalw * 16;
    const int T = (N_ATOMS + step - 1) / step;
    unsigned* Aw = &Ap[w * 16 * 36];

    for (int t = 0; t < T; ++t) {
        int base = gw * 16 + t * step;
        #pragma unroll
        for (int sub = 0; sub < 4; ++sub) {
            int chunk = g * 4 + sub;          // 16 float4 chunks per row
            int a = base + r;
            float4 v = make_float4(0.f, 0.f, 0.f, 0.f);
            if (a < N_ATOMS)
                v = reinterpret_cast<const float4*>(atom)[a * 16 + chunk];
            unsigned d0 = pack_bf2(v.x, v.y);
            unsigned d1 = pack_bf2(v.z, v.w);
            Aw[r * 36 + chunk * 2]     = d0;
            Aw[r * 36 + chunk * 2 + 1] = d1;
            if (a < N_ATOMS) {
                abf_u32[a * 32 + chunk * 2]     = d0;
                abf_u32[a * 32 + chunk * 2 + 1] = d1;
            }
        }
        __syncthreads();
        short8 af[2];
        #pragma unroll
        for (int kk = 0; kk < 2; ++kk) {
            union { uint4 u; short8 s; } u;
            u.u = *reinterpret_cast<const uint4*>(&Aw[r * 36 + kk * 16 + g * 4]);
            af[kk] = u.s;
        }
        #pragma unroll
        for (int nt = 0; nt < 8; ++nt) {
            f32x4 acc = {0.f, 0.f, 0.f, 0.f};
            acc = __builtin_amdgcn_mfma_f32_16x16x32_bf16(af[0], bf[nt][0], acc, 0, 0, 0);
            acc = __builtin_amdgcn_mfma_f32_16x16x32_bf16(af[1], bf[nt][1], acc, 0, 0, 0);
            int col = nt * 16 + r;
            float bb = bias[col];
            #pragma unroll
            for (int r4 = 0; r4 < 4; ++r4) {
                int a = base + g * 4 + r4;    // C row = quad*4 + reg
                if (a < N_ATOMS)
                    A1b[a * OUT_DIM + col] = f2bf(acc[r4] + bb);
            }
        }
        __syncthreads();
    }
}

// ---------------------------------------------------------------------------
// M: one wave per atom per iteration. A-tile = [12 nbr rows + 4 pad] x K128
// bf16 ([abf_j | edge | 0]); B (regs) = [W_nbr | W_edge | 0]^T.
// z = MFMA + A1; msg = sum_m sigmoid(zf)*softplus(zc); X = atom_fea + msg.
// ---------------------------------------------------------------------------
__global__ __launch_bounds__(256, 2) void k_msg(
    const float* __restrict__ atom, const float* __restrict__ nbr,
    const float* __restrict__ W, const int* __restrict__ idx,
    const unsigned* __restrict__ abf_u32, const unsigned short* __restrict__ A1b,
    float* __restrict__ X)
{
    __shared__ unsigned Au[4 * 16 * 68];  // per-wave 16 rows x 68 dw (128 bf16 + pad)
    const int tid = threadIdx.x;
    const int w = tid >> 6, l = tid & 63;
    const int c = l & 15, g = l >> 4;
    unsigned* Aw = &Au[w * 16 * 68];

    // B fragments in registers (held across the whole kernel): 128 VGPRs
    short8 bf[8][4];
    #pragma unroll
    for (int nt = 0; nt < 8; ++nt)
      #pragma unroll
      for (int kk = 0; kk < 4; ++kk)
        #pragma unroll
        for (int j = 0; j < 8; ++j) {
            int col = nt * 16 + c;
            int k = g * 8 + kk * 32 + j;
            float wv = (k < 105) ? W[col * IN_DIM + 64 + k] : 0.f;  // nbr|edge blocks
            bf[nt][kk][j] = (short)f2bf(wv);
        }

    // zero pad rows 12..15 once (never rewritten)
    for (int t = l; t < 4 * 68; t += 64)
        Aw[12 * 68 + t] = 0u;

    const int totalw = gridDim.x * 4;
    const int gw = blockIdx.x * 4 + w;
    const int T = (N_ATOMS + totalw - 1) / totalw;

    for (int t = 0; t < T; ++t) {
        int i = gw + t * totalw;
        bool act = (i < N_ATOMS);
        if (act) {
            // phase 1: gather neighbor bf16 features -> k 0..63 (dw 0..31)
            #pragma unroll
            for (int rr = 0; rr < 3; ++rr) {
                int r = rr * 4 + g;
                int j = idx[i * M_NBRS + r];
                Aw[r * 68 + c]      = abf_u32[j * 32 + c];
                Aw[r * 68 + 16 + c] = abf_u32[j * 32 + 16 + c];
            }
            // phase 2: edge fp32 -> bf16 -> k 64..127 (dw 32..63)
            #pragma unroll
            for (int rr = 0; rr < 3; ++rr) {
                int r = rr * 4 + g;
                int eb = (i * M_NBRS + r) * NBR_F;
                float f0 = nbr[eb + 2 * c];
                float f1 = nbr[eb + 2 * c + 1];          // 2c+1 <= 31 < 41, safe
                Aw[r * 68 + 32 + c] = pack_bf2(f0, f1);
                int cc = c + 16;                          // dw 48..63
                unsigned d = 0u;
                if (cc < 21) {                            // bf16 k 96..105
                    float h0 = nbr[eb + 2 * cc];
                    float h1 = (2 * cc + 1 < NBR_F) ? nbr[eb + 2 * cc + 1] : 0.f;
                    d = pack_bf2(h0, h1);
                }
                Aw[r * 68 + 32 + cc] = d;
            }
        }
        __syncthreads();
        short8 af[4];
        #pragma unroll
        for (int kk = 0; kk < 4; ++kk) {
            union { uint4 u; short8 s; } u;
            u.u = *reinterpret_cast<const uint4*>(&Aw[c * 68 + kk * 16 + g * 4]);
            af[kk] = u.s;
        }
        if (act) {
            #pragma unroll
            for (int p = 0; p < 4; ++p) {
                f32x4 accf = {0.f,0.f,0.f,0.f}, accc = {0.f,0.f,0.f,0.f};
                #pragma unroll
                for (int kk = 0; kk < 4; ++kk) {
                    accf = __builtin_amdgcn_mfma_f32_16x16x32_bf16(af[kk], bf[p][kk],     accf, 0,0,0);
                    accc = __builtin_amdgcn_mfma_f32_16x16x32_bf16(af[kk], bf[p + 4][kk], accc, 0,0,0);
                }
                int col = p * 16 + c;
                float a1f = bf2f(A1b[i * OUT_DIM + col]);
                float a1c = bf2f(A1b[i * OUT_DIM + 64 + col]);
                float gs = 0.f;
                if (g < 3) {   // rows 12..15 (pad) are exactly quad 3
                    #pragma unroll
                    for (int r4 = 0; r4 < 4; ++r4) {
                        float zf = accf[r4] + a1f;
                        float zc = accc[r4] + a1c;
                        gs += sigmoid_f(zf) * softplus_f(zc);
                    }
                }
                gs += __shfl_xor(gs, 16, 64);
                gs += __shfl_xor(gs, 32, 64);
                if (g == 0)
                    X[i * ATOM_F + col] = atom[i * ATOM_F + col] + gs;
            }
        }
        __syncthreads();
    }
}

// ---------------------------------------------------------------------------
// BN stats, two stages, then in-place normalize + softplus.
// ---------------------------------------------------------------------------
__global__ void k_stats1(const float* __restrict__ X, float* __restrict__ PART)
{
    __shared__ float s1[256], s2[256];
    int tid = threadIdx.x;
    int f = tid & 63;
    int seg = blockIdx.x * 4 + (tid >> 6);   // 512 segments
    float sum = 0.f, sq = 0.f;
    for (int a = seg; a < N_ATOMS; a += 512) {
        float x = X[a * ATOM_F + f];
        sum += x; sq += x * x;
    }
    s1[tid] = sum; s2[tid] = sq;
    __syncthreads();
    if (tid < 64) {
        PART[blockIdx.x * 128 + tid] = s1[tid] + s1[tid+64] + s1[tid+128] + s1[tid+192];
    } else if (tid < 128) {
        int ff = tid - 64;
        PART[blockIdx.x * 128 + tid] = s2[ff] + s2[ff+64] + s2[ff+128] + s2[ff+192];
    }
}

__global__ void k_stats2(const float* __restrict__ PART, const float* __restrict__ gamma,
                         const float* __restrict__ beta, float* __restrict__ MS)
{
    __shared__ float st[128];
    int t = threadIdx.x;
    float s = 0.f;
    #pragma unroll 8
    for (int b = 0; b < 128; ++b) s += PART[b * 128 + t];
    st[t] = s;
    __syncthreads();
    if (t < 64) {
        float mean = st[t] * (1.f / N_ATOMS);
        float msq  = st[64 + t] * (1.f / N_ATOMS);
        float var  = msq - mean * mean;        // biased var, matches jnp.var
        float inv  = rsqrtf(var + 1e-5f);
        float sc   = inv * gamma[t];
        float sh   = beta[t] - mean * sc;
        MS[t] = sc;
        MS[64 + t] = sh;
    }
}

__global__ void k_final(float* __restrict__ X, const float* __restrict__ MS)
{
    int q = blockIdx.x * 256 + threadIdx.x;   // exactly N*64/4 threads
    const float4* MS4 = reinterpret_cast<const float4*>(MS);
    float4 x = reinterpret_cast<const float4*>(X)[q];
    float4 sc = MS4[q & 15];
    float4 sh = MS4[16 + (q & 15)];
    float4 o;
    o.x = softplus_f(x.x * sc.x + sh.x);
    o.y = softplus_f(x.y * sc.y + sh.y);
    o.z = softplus_f(x.z * sc.z + sh.z);
    o.w = softplus_f(x.w * sc.w + sh.w);
    reinterpret_cast<float4*>(X)[q] = o;
}

extern "C" void kernel_launch(void* const* d_in, const int* in_sizes, int n_in,
                              void* d_out, int out_size, void* d_ws, size_t ws_size,
                              hipStream_t stream)
{
    const float* atom  = (const float*)d_in[0];
    const float* nbr   = (const float*)d_in[1];
    const float* W     = (const float*)d_in[2];
    const float* bias  = (const float*)d_in[3];
    const float* gamma = (const float*)d_in[4];
    const float* beta  = (const float*)d_in[5];
    const int*   idx   = (const int*)d_in[6];
    float* X = (float*)d_out;   // x pre-BN lives in d_out, finalized in place

    char* ws = (char*)d_ws;
    unsigned* abf       = (unsigned*)ws;                               // N*64 bf16
    unsigned short* A1b = (unsigned short*)(ws + (size_t)N_ATOMS * 64 * 2);  // N*128 bf16
    float* PART         = (float*)(ws + (size_t)N_ATOMS * 64 * 2
                                      + (size_t)N_ATOMS * 128 * 2);    // 128*128 f32
    float* MS           = PART + 128 * 128;                            // 128 f32

    hipLaunchKernelGGL(k_prep,   dim3(1024), dim3(256), 0, stream, atom, W, bias, abf, A1b);
    hipLaunchKernelGGL(k_msg,    dim3(1024), dim3(256), 0, stream, atom, nbr, W, idx, abf, A1b, X);
    hipLaunchKernelGGL(k_stats1, dim3(128),  dim3(256), 0, stream, X, PART);
    hipLaunchKernelGGL(k_stats2, dim3(1),    dim3(128), 0, stream, PART, gamma, beta, MS);
    hipLaunchKernelGGL(k_final,  dim3(6250), dim3(256), 0, stream, X, MS);
}